// Round 5
// baseline (546.958 us; speedup 1.0000x reference)
//
#include <hip/hip_runtime.h>

// GraphEmbedder: B=8, C=64, G=65536, 4 layers of y=lrelu(W@[x; x-x0]), then max over G.
// Identity: W@[x; x-x0] = Wa@x - Wb@x0, Wa = W[:,:64]+W[:,64:], Wb = W[:,64:].
// bias chain (exact fp32) in prep; main = register-resident 4-layer f16 MFMA chain.
// R5: 512-thread blocks (8 waves, 64 cols/wave) -> 4 blocks/CU x 8 waves = 32 waves/CU
// (R4 was 16); launch_bounds(512,8) pins VGPR=64 (R4-proven body); prep 9-way parallel.

#define G_TOT 65536

typedef _Float16 hf2 __attribute__((ext_vector_type(2)));
typedef _Float16 hf4 __attribute__((ext_vector_type(4)));
typedef _Float16 hf8 __attribute__((ext_vector_type(8)));
typedef float float4_ __attribute__((ext_vector_type(4)));

static __device__ __forceinline__ hf2 pkh(float x, float y) {
    return __builtin_bit_cast(hf2, __builtin_amdgcn_cvt_pkrtz(x, y));
}

// ws layout (floats):
//   [0, 16384)      Wa[l][o][c] fp32
//   [16384, 18432)  nbias[b][l][o] fp32 (NEGATED bias)
//   [18432, 18944)  maxenc (uint32 ordered-float), zeroed by prep

__global__ __launch_bounds__(256) void ge_prep(
    const float* __restrict__ feat,
    const float* __restrict__ W0, const float* __restrict__ W1,
    const float* __restrict__ W2, const float* __restrict__ W3,
    float* __restrict__ ws)
{
    const int tid = threadIdx.x;
    const int blk = blockIdx.x;
    __shared__ float lw[64][129];
    __shared__ float x0[2][64];

    if (blk == 8) {
        // maxenc init + Wa = W[:,:64] + W[:,64:]
        unsigned* maxenc = (unsigned*)(ws + 18432);
        maxenc[tid] = 0u; maxenc[tid + 256] = 0u;
        for (int i = tid; i < 4 * 64 * 64; i += 256) {
            int l = i >> 12, o = (i >> 6) & 63, c = i & 63;
            const float* Wl = (l == 0) ? W0 : (l == 1) ? W1 : (l == 2) ? W2 : W3;
            ws[i] = Wl[o * 128 + c] + Wl[o * 128 + 64 + c];
        }
        return;
    }

    // blocks 0..7: exact fp32 bias chain for batch b = blk
    const int b = blk;
    if (tid < 64) x0[0][tid] = feat[(size_t)(b * 64 + tid) * G_TOT];
    float* nbias = ws + 16384;
    for (int l = 0; l < 4; ++l) {
        const float* Wl = (l == 0) ? W0 : (l == 1) ? W1 : (l == 2) ? W2 : W3;
        for (int i = tid; i < 64 * 128; i += 256) lw[i >> 7][i & 127] = Wl[i];
        __syncthreads();
        if (tid < 64) {
            const int o = tid;
            const float* src = x0[l & 1];
            float s1 = 0.f, s2 = 0.f;
            for (int c = 0; c < 64; ++c) {
                float xv = src[c];
                s1 += lw[o][c] * xv;
                s2 += lw[o][64 + c] * xv;
            }
            nbias[b * 256 + l * 64 + o] = -s2;          // negated, [b][l][o]
            x0[(l & 1) ^ 1][o] = fmaxf(s1, 0.1f * s1);
        }
        __syncthreads();
    }
}

__global__ __launch_bounds__(512, 8) void ge_main(
    const float* __restrict__ feat,
    const float* __restrict__ ws_wa,
    const float* __restrict__ nbias,
    unsigned* __restrict__ maxenc)
{
    // pr-major f16 weights: fragment f = ((l*4+mt)*2+pr); lane reads 16B at
    // (f*64+lane)*16 -> 16B lane stride, conflict-free ds_read_b128.
    __shared__ _Float16 lws[16384];
    __shared__ float lbias[256];
    __shared__ float blockmax[8][64];
    const int tid = threadIdx.x;
    const int b = blockIdx.x >> 7;      // 128 blocks per batch, 512 cols each

    for (int gi = tid; gi < 4096; gi += 512) {   // gi indexes hf4 chunks
        int hi = gi & 1, ln = (gi >> 1) & 63, f = gi >> 7;
        int pr = f & 1, mt = (f >> 1) & 3, l = f >> 3;
        int o = (mt << 4) + (ln & 15);
        int c = (((pr << 1) + hi) << 4) + ((ln >> 4) << 2);
        float4_ wv = *(const float4_*)&ws_wa[((l << 6) + o) * 64 + c];
        union { hf2 h2[2]; hf4 h4; } u;
        u.h2[0] = pkh(wv[0], wv[1]);
        u.h2[1] = pkh(wv[2], wv[3]);
        *(hf4*)&lws[gi << 2] = u.h4;
    }
    if (tid < 256) lbias[tid] = nbias[(b << 8) + tid];
    __syncthreads();

    const int w = tid >> 6, lane = tid & 63, q = lane >> 4, n = lane & 15;
    const int g0 = ((blockIdx.x & 127) << 9) + (w << 6);   // 64 cols per wave
    const float* Xrow = feat + (size_t)b * 64 * G_TOT + (size_t)(q << 2) * G_TOT;
    const hf4 k01 = { (_Float16)0.1f, (_Float16)0.1f, (_Float16)0.1f, (_Float16)0.1f };

    float rmax[4][4];
#pragma unroll
    for (int mt = 0; mt < 4; ++mt)
#pragma unroll
        for (int j = 0; j < 4; ++j) rmax[mt][j] = -__builtin_inff();

    float cur[16];
    {
        int gcol = g0 + n;
#pragma unroll
        for (int kf = 0; kf < 4; ++kf)
#pragma unroll
            for (int r = 0; r < 4; ++r)
                cur[kf * 4 + r] = Xrow[(size_t)((kf << 4) + r) * G_TOT + gcol];
    }

#pragma unroll 1
    for (int nt = 0; nt < 4; ++nt) {
        // branchless prefetch: nt=3 wraps to tile 0 (L2 hit, result discarded)
        float nxt[16];
        {
            int gcol = g0 + (((nt + 1) & 3) << 4) + n;
#pragma unroll
            for (int kf = 0; kf < 4; ++kf)
#pragma unroll
                for (int r = 0; r < 4; ++r)
                    nxt[kf * 4 + r] = Xrow[(size_t)((kf << 4) + r) * G_TOT + gcol];
        }

        hf4 bf[4];
#pragma unroll
        for (int kf = 0; kf < 4; ++kf) {
            union { hf2 h2[2]; hf4 h4; } u;
            u.h2[0] = pkh(cur[kf * 4 + 0], cur[kf * 4 + 1]);
            u.h2[1] = pkh(cur[kf * 4 + 2], cur[kf * 4 + 3]);
            bf[kf] = u.h4;
        }

#pragma unroll
        for (int l = 0; l < 4; ++l) {
            float4_ acc[4];
#pragma unroll
            for (int mt = 0; mt < 4; ++mt)  // acc init = -bias (quad-broadcast b128)
                acc[mt] = *(const float4_*)&lbias[(l << 6) + (mt << 4) + (q << 2)];
#pragma unroll
            for (int mt = 0; mt < 4; ++mt) {
#pragma unroll
                for (int pr = 0; pr < 2; ++pr) {
                    union { hf8 h8; hf4 h4[2]; } ua;
                    ua.h8 = *(const hf8*)&lws[((((((l << 2) + mt) << 1) + pr) << 6) + lane) << 3];
                    acc[mt] = __builtin_amdgcn_mfma_f32_16x16x16f16(ua.h4[0], bf[(pr << 1) + 0], acc[mt], 0, 0, 0);
                    acc[mt] = __builtin_amdgcn_mfma_f32_16x16x16f16(ua.h4[1], bf[(pr << 1) + 1], acc[mt], 0, 0, 0);
                }
            }
            if (l < 3) {
#pragma unroll
                for (int mt = 0; mt < 4; ++mt) {   // packed-f16 leaky-relu
                    union { hf2 h2[2]; hf4 h4; } u;
                    u.h2[0] = pkh(acc[mt][0], acc[mt][1]);
                    u.h2[1] = pkh(acc[mt][2], acc[mt][3]);
                    hf4 h = u.h4;
                    h = __builtin_elementwise_max(h, h * k01);
                    bf[mt] = h;   // D rows of tile mt == next-layer K-chunk mt
                }
            } else {
#pragma unroll
                for (int mt = 0; mt < 4; ++mt)
#pragma unroll
                    for (int j = 0; j < 4; ++j) {
                        float y = acc[mt][j];
                        rmax[mt][j] = fmaxf(rmax[mt][j], fmaxf(y, 0.1f * y));
                    }
            }
        }
#pragma unroll
        for (int i = 0; i < 16; ++i) cur[i] = nxt[i];
    }

    // reduce over 16 column-lanes
#pragma unroll
    for (int mt = 0; mt < 4; ++mt)
#pragma unroll
        for (int j = 0; j < 4; ++j) {
            float v = rmax[mt][j];
            v = fmaxf(v, __shfl_xor(v, 1, 64));
            v = fmaxf(v, __shfl_xor(v, 2, 64));
            v = fmaxf(v, __shfl_xor(v, 4, 64));
            v = fmaxf(v, __shfl_xor(v, 8, 64));
            rmax[mt][j] = v;
        }
    if (n == 0) {
#pragma unroll
        for (int mt = 0; mt < 4; ++mt)
#pragma unroll
            for (int j = 0; j < 4; ++j)
                blockmax[w][(mt << 4) + (q << 2) + j] = rmax[mt][j];
    }
    __syncthreads();
    if (tid < 64) {
        float v = blockmax[0][tid];
#pragma unroll
        for (int ww = 1; ww < 8; ++ww) v = fmaxf(v, blockmax[ww][tid]);
        unsigned s = __float_as_uint(v);
        unsigned enc = (s & 0x80000000u) ? ~s : (s | 0x80000000u);
        atomicMax(&maxenc[b * 64 + tid], enc);
    }
}

__global__ void ge_final(const unsigned* __restrict__ maxenc, float* __restrict__ out)
{
    int i = threadIdx.x;
    if (i < 512) {
        unsigned u = maxenc[i];
        unsigned s = (u & 0x80000000u) ? (u ^ 0x80000000u) : ~u;
        out[i] = __uint_as_float(s);
    }
}

extern "C" void kernel_launch(void* const* d_in, const int* in_sizes, int n_in,
                              void* d_out, int out_size, void* d_ws, size_t ws_size,
                              hipStream_t stream) {
    const float* feat = (const float*)d_in[0];
    const float* W0 = (const float*)d_in[1];
    const float* W1 = (const float*)d_in[2];
    const float* W2 = (const float*)d_in[3];
    const float* W3 = (const float*)d_in[4];
    float* ws = (float*)d_ws;
    unsigned* maxenc = (unsigned*)(ws + 18432);

    ge_prep<<<9, 256, 0, stream>>>(feat, W0, W1, W2, W3, ws);
    ge_main<<<1024, 512, 0, stream>>>(feat, ws, ws + 16384, maxenc);
    ge_final<<<1, 512, 0, stream>>>(maxenc, (float*)d_out);
}

// Round 6
// 392.649 us; speedup vs baseline: 1.3930x; 1.3930x over previous
//
#include <hip/hip_runtime.h>

// GraphEmbedder: B=8, C=64, G=65536, 4 layers of y=lrelu(W@[x; x-x0]), then max over G.
// Identity: W@[x; x-x0] = Wa@x - Wb@x0, Wa = W[:,:64]+W[:,64:], Wb = W[:,64:].
// bias chain (exact fp32) in prep; main = register-resident 4-layer f16 MFMA chain.
// R6: R5 structure (512-thr blocks, 8 waves, 64 cols/wave) but launch_bounds(512,4):
// VGPR cap 128 >= natural 64 -> no spill (R5's (512,8) forced 32 VGPR + scratch);
// occupancy then set by resources: VGPR 64 & LDS 35.8KB -> 4 blocks x 8 waves = 32 waves/CU.

#define G_TOT 65536

typedef _Float16 hf2 __attribute__((ext_vector_type(2)));
typedef _Float16 hf4 __attribute__((ext_vector_type(4)));
typedef _Float16 hf8 __attribute__((ext_vector_type(8)));
typedef float float4_ __attribute__((ext_vector_type(4)));

static __device__ __forceinline__ hf2 pkh(float x, float y) {
    return __builtin_bit_cast(hf2, __builtin_amdgcn_cvt_pkrtz(x, y));
}

// ws layout (floats):
//   [0, 16384)      Wa[l][o][c] fp32
//   [16384, 18432)  nbias[b][l][o] fp32 (NEGATED bias)
//   [18432, 18944)  maxenc (uint32 ordered-float), zeroed by prep

__global__ __launch_bounds__(256) void ge_prep(
    const float* __restrict__ feat,
    const float* __restrict__ W0, const float* __restrict__ W1,
    const float* __restrict__ W2, const float* __restrict__ W3,
    float* __restrict__ ws)
{
    const int tid = threadIdx.x;
    const int blk = blockIdx.x;
    __shared__ float lw[64][129];
    __shared__ float x0[2][64];

    if (blk == 8) {
        // maxenc init + Wa = W[:,:64] + W[:,64:]
        unsigned* maxenc = (unsigned*)(ws + 18432);
        maxenc[tid] = 0u; maxenc[tid + 256] = 0u;
        for (int i = tid; i < 4 * 64 * 64; i += 256) {
            int l = i >> 12, o = (i >> 6) & 63, c = i & 63;
            const float* Wl = (l == 0) ? W0 : (l == 1) ? W1 : (l == 2) ? W2 : W3;
            ws[i] = Wl[o * 128 + c] + Wl[o * 128 + 64 + c];
        }
        return;
    }

    // blocks 0..7: exact fp32 bias chain for batch b = blk
    const int b = blk;
    if (tid < 64) x0[0][tid] = feat[(size_t)(b * 64 + tid) * G_TOT];
    float* nbias = ws + 16384;
    for (int l = 0; l < 4; ++l) {
        const float* Wl = (l == 0) ? W0 : (l == 1) ? W1 : (l == 2) ? W2 : W3;
        for (int i = tid; i < 64 * 128; i += 256) lw[i >> 7][i & 127] = Wl[i];
        __syncthreads();
        if (tid < 64) {
            const int o = tid;
            const float* src = x0[l & 1];
            float s1 = 0.f, s2 = 0.f;
            for (int c = 0; c < 64; ++c) {
                float xv = src[c];
                s1 += lw[o][c] * xv;
                s2 += lw[o][64 + c] * xv;
            }
            nbias[b * 256 + l * 64 + o] = -s2;          // negated, [b][l][o]
            x0[(l & 1) ^ 1][o] = fmaxf(s1, 0.1f * s1);
        }
        __syncthreads();
    }
}

__global__ __launch_bounds__(512, 4) void ge_main(
    const float* __restrict__ feat,
    const float* __restrict__ ws_wa,
    const float* __restrict__ nbias,
    unsigned* __restrict__ maxenc)
{
    // pr-major f16 weights: fragment f = ((l*4+mt)*2+pr); lane reads 16B at
    // (f*64+lane)*16 -> 16B lane stride, conflict-free ds_read_b128.
    __shared__ _Float16 lws[16384];
    __shared__ float lbias[256];
    __shared__ float blockmax[8][64];
    const int tid = threadIdx.x;
    const int b = blockIdx.x >> 7;      // 128 blocks per batch, 512 cols each

    for (int gi = tid; gi < 4096; gi += 512) {   // gi indexes hf4 chunks
        int hi = gi & 1, ln = (gi >> 1) & 63, f = gi >> 7;
        int pr = f & 1, mt = (f >> 1) & 3, l = f >> 3;
        int o = (mt << 4) + (ln & 15);
        int c = (((pr << 1) + hi) << 4) + ((ln >> 4) << 2);
        float4_ wv = *(const float4_*)&ws_wa[((l << 6) + o) * 64 + c];
        union { hf2 h2[2]; hf4 h4; } u;
        u.h2[0] = pkh(wv[0], wv[1]);
        u.h2[1] = pkh(wv[2], wv[3]);
        *(hf4*)&lws[gi << 2] = u.h4;
    }
    if (tid < 256) lbias[tid] = nbias[(b << 8) + tid];
    __syncthreads();

    const int w = tid >> 6, lane = tid & 63, q = lane >> 4, n = lane & 15;
    const int g0 = ((blockIdx.x & 127) << 9) + (w << 6);   // 64 cols per wave
    const float* Xrow = feat + (size_t)b * 64 * G_TOT + (size_t)(q << 2) * G_TOT;
    const hf4 k01 = { (_Float16)0.1f, (_Float16)0.1f, (_Float16)0.1f, (_Float16)0.1f };

    float rmax[4][4];
#pragma unroll
    for (int mt = 0; mt < 4; ++mt)
#pragma unroll
        for (int j = 0; j < 4; ++j) rmax[mt][j] = -__builtin_inff();

    float cur[16];
    {
        int gcol = g0 + n;
#pragma unroll
        for (int kf = 0; kf < 4; ++kf)
#pragma unroll
            for (int r = 0; r < 4; ++r)
                cur[kf * 4 + r] = Xrow[(size_t)((kf << 4) + r) * G_TOT + gcol];
    }

#pragma unroll 1
    for (int nt = 0; nt < 4; ++nt) {
        // branchless prefetch: nt=3 wraps to tile 0 (L2 hit, result discarded)
        float nxt[16];
        {
            int gcol = g0 + (((nt + 1) & 3) << 4) + n;
#pragma unroll
            for (int kf = 0; kf < 4; ++kf)
#pragma unroll
                for (int r = 0; r < 4; ++r)
                    nxt[kf * 4 + r] = Xrow[(size_t)((kf << 4) + r) * G_TOT + gcol];
        }

        hf4 bf[4];
#pragma unroll
        for (int kf = 0; kf < 4; ++kf) {
            union { hf2 h2[2]; hf4 h4; } u;
            u.h2[0] = pkh(cur[kf * 4 + 0], cur[kf * 4 + 1]);
            u.h2[1] = pkh(cur[kf * 4 + 2], cur[kf * 4 + 3]);
            bf[kf] = u.h4;
        }

#pragma unroll
        for (int l = 0; l < 4; ++l) {
            float4_ acc[4];
#pragma unroll
            for (int mt = 0; mt < 4; ++mt)  // acc init = -bias (quad-broadcast b128)
                acc[mt] = *(const float4_*)&lbias[(l << 6) + (mt << 4) + (q << 2)];
#pragma unroll
            for (int mt = 0; mt < 4; ++mt) {
#pragma unroll
                for (int pr = 0; pr < 2; ++pr) {
                    union { hf8 h8; hf4 h4[2]; } ua;
                    ua.h8 = *(const hf8*)&lws[((((((l << 2) + mt) << 1) + pr) << 6) + lane) << 3];
                    acc[mt] = __builtin_amdgcn_mfma_f32_16x16x16f16(ua.h4[0], bf[(pr << 1) + 0], acc[mt], 0, 0, 0);
                    acc[mt] = __builtin_amdgcn_mfma_f32_16x16x16f16(ua.h4[1], bf[(pr << 1) + 1], acc[mt], 0, 0, 0);
                }
            }
            if (l < 3) {
#pragma unroll
                for (int mt = 0; mt < 4; ++mt) {   // packed-f16 leaky-relu
                    union { hf2 h2[2]; hf4 h4; } u;
                    u.h2[0] = pkh(acc[mt][0], acc[mt][1]);
                    u.h2[1] = pkh(acc[mt][2], acc[mt][3]);
                    hf4 h = u.h4;
                    h = __builtin_elementwise_max(h, h * k01);
                    bf[mt] = h;   // D rows of tile mt == next-layer K-chunk mt
                }
            } else {
#pragma unroll
                for (int mt = 0; mt < 4; ++mt)
#pragma unroll
                    for (int j = 0; j < 4; ++j) {
                        float y = acc[mt][j];
                        rmax[mt][j] = fmaxf(rmax[mt][j], fmaxf(y, 0.1f * y));
                    }
            }
        }
#pragma unroll
        for (int i = 0; i < 16; ++i) cur[i] = nxt[i];
    }

    // reduce over 16 column-lanes
#pragma unroll
    for (int mt = 0; mt < 4; ++mt)
#pragma unroll
        for (int j = 0; j < 4; ++j) {
            float v = rmax[mt][j];
            v = fmaxf(v, __shfl_xor(v, 1, 64));
            v = fmaxf(v, __shfl_xor(v, 2, 64));
            v = fmaxf(v, __shfl_xor(v, 4, 64));
            v = fmaxf(v, __shfl_xor(v, 8, 64));
            rmax[mt][j] = v;
        }
    if (n == 0) {
#pragma unroll
        for (int mt = 0; mt < 4; ++mt)
#pragma unroll
            for (int j = 0; j < 4; ++j)
                blockmax[w][(mt << 4) + (q << 2) + j] = rmax[mt][j];
    }
    __syncthreads();
    if (tid < 64) {
        float v = blockmax[0][tid];
#pragma unroll
        for (int ww = 1; ww < 8; ++ww) v = fmaxf(v, blockmax[ww][tid]);
        unsigned s = __float_as_uint(v);
        unsigned enc = (s & 0x80000000u) ? ~s : (s | 0x80000000u);
        atomicMax(&maxenc[b * 64 + tid], enc);
    }
}

__global__ void ge_final(const unsigned* __restrict__ maxenc, float* __restrict__ out)
{
    int i = threadIdx.x;
    if (i < 512) {
        unsigned u = maxenc[i];
        unsigned s = (u & 0x80000000u) ? (u ^ 0x80000000u) : ~u;
        out[i] = __uint_as_float(s);
    }
}

extern "C" void kernel_launch(void* const* d_in, const int* in_sizes, int n_in,
                              void* d_out, int out_size, void* d_ws, size_t ws_size,
                              hipStream_t stream) {
    const float* feat = (const float*)d_in[0];
    const float* W0 = (const float*)d_in[1];
    const float* W1 = (const float*)d_in[2];
    const float* W2 = (const float*)d_in[3];
    const float* W3 = (const float*)d_in[4];
    float* ws = (float*)d_ws;
    unsigned* maxenc = (unsigned*)(ws + 18432);

    ge_prep<<<9, 256, 0, stream>>>(feat, W0, W1, W2, W3, ws);
    ge_main<<<1024, 512, 0, stream>>>(feat, ws, ws + 16384, maxenc);
    ge_final<<<1, 512, 0, stream>>>(maxenc, (float*)d_out);
}

// Round 7
// 221.061 us; speedup vs baseline: 2.4742x; 1.7762x over previous
//
#include <hip/hip_runtime.h>

// GraphEmbedder: B=8, C=64, G=65536, 4 layers of y=lrelu(W@[x; x-x0]), then max over G.
// Identity: W@[x; x-x0] = Wa@x - Wb@x0, Wa = W[:,:64]+W[:,64:], Wb = W[:,64:].
// bias chain (exact fp32) in prep; main = register-resident 4-layer f16 MFMA chain.
// R7 = R4 config exactly (256 thr, launch_bounds(256,2), 128 cols/wave -> 128 VGPR,
// 16 waves/CU, spill-free; R5/R6 proved larger blocks force spill) plus:
//  - deferred lrelu on final layer (max commutes with monotone lrelu): -32 VALU/nt
//  - guarded prefetch (skip wrap refetch): -16 loads/wave
//  - parallel 9-block prep (from R5/R6, proven)

#define G_TOT 65536

typedef _Float16 hf2 __attribute__((ext_vector_type(2)));
typedef _Float16 hf4 __attribute__((ext_vector_type(4)));
typedef _Float16 hf8 __attribute__((ext_vector_type(8)));
typedef float float4_ __attribute__((ext_vector_type(4)));

static __device__ __forceinline__ hf2 pkh(float x, float y) {
    return __builtin_bit_cast(hf2, __builtin_amdgcn_cvt_pkrtz(x, y));
}

// ws layout (floats):
//   [0, 16384)      Wa[l][o][c] fp32
//   [16384, 18432)  nbias[b][l][o] fp32 (NEGATED bias)
//   [18432, 18944)  maxenc (uint32 ordered-float), zeroed by prep

__global__ __launch_bounds__(256) void ge_prep(
    const float* __restrict__ feat,
    const float* __restrict__ W0, const float* __restrict__ W1,
    const float* __restrict__ W2, const float* __restrict__ W3,
    float* __restrict__ ws)
{
    const int tid = threadIdx.x;
    const int blk = blockIdx.x;
    __shared__ float lw[64][129];
    __shared__ float x0[2][64];

    if (blk == 8) {
        // maxenc init + Wa = W[:,:64] + W[:,64:]
        unsigned* maxenc = (unsigned*)(ws + 18432);
        maxenc[tid] = 0u; maxenc[tid + 256] = 0u;
        for (int i = tid; i < 4 * 64 * 64; i += 256) {
            int l = i >> 12, o = (i >> 6) & 63, c = i & 63;
            const float* Wl = (l == 0) ? W0 : (l == 1) ? W1 : (l == 2) ? W2 : W3;
            ws[i] = Wl[o * 128 + c] + Wl[o * 128 + 64 + c];
        }
        return;
    }

    // blocks 0..7: exact fp32 bias chain for batch b = blk
    const int b = blk;
    if (tid < 64) x0[0][tid] = feat[(size_t)(b * 64 + tid) * G_TOT];
    float* nbias = ws + 16384;
    for (int l = 0; l < 4; ++l) {
        const float* Wl = (l == 0) ? W0 : (l == 1) ? W1 : (l == 2) ? W2 : W3;
        for (int i = tid; i < 64 * 128; i += 256) lw[i >> 7][i & 127] = Wl[i];
        __syncthreads();
        if (tid < 64) {
            const int o = tid;
            const float* src = x0[l & 1];
            float s1 = 0.f, s2 = 0.f;
            for (int c = 0; c < 64; ++c) {
                float xv = src[c];
                s1 += lw[o][c] * xv;
                s2 += lw[o][64 + c] * xv;
            }
            nbias[b * 256 + l * 64 + o] = -s2;          // negated, [b][l][o]
            x0[(l & 1) ^ 1][o] = fmaxf(s1, 0.1f * s1);
        }
        __syncthreads();
    }
}

__global__ __launch_bounds__(256, 2) void ge_main(
    const float* __restrict__ feat,
    const float* __restrict__ ws_wa,
    const float* __restrict__ nbias,
    unsigned* __restrict__ maxenc)
{
    // pr-major f16 weights: fragment f = ((l*4+mt)*2+pr); lane reads 16B at
    // (f*64+lane)*16 -> 16B lane stride, conflict-free ds_read_b128.
    __shared__ _Float16 lws[16384];
    __shared__ float lbias[256];
    __shared__ float blockmax[4][64];
    const int tid = threadIdx.x;
    const int b = blockIdx.x >> 7;      // 128 blocks per batch, 512 cols each

    for (int gi = tid; gi < 4096; gi += 256) {   // gi indexes hf4 chunks
        int hi = gi & 1, ln = (gi >> 1) & 63, f = gi >> 7;
        int pr = f & 1, mt = (f >> 1) & 3, l = f >> 3;
        int o = (mt << 4) + (ln & 15);
        int c = (((pr << 1) + hi) << 4) + ((ln >> 4) << 2);
        float4_ wv = *(const float4_*)&ws_wa[((l << 6) + o) * 64 + c];
        union { hf2 h2[2]; hf4 h4; } u;
        u.h2[0] = pkh(wv[0], wv[1]);
        u.h2[1] = pkh(wv[2], wv[3]);
        *(hf4*)&lws[gi << 2] = u.h4;
    }
    lbias[tid] = nbias[(b << 8) + tid];
    __syncthreads();

    const int w = tid >> 6, lane = tid & 63, q = lane >> 4, n = lane & 15;
    const int g0 = ((blockIdx.x & 127) << 9) + (w << 7);   // 128 cols per wave
    const float* Xrow = feat + (size_t)b * 64 * G_TOT + (size_t)(q << 2) * G_TOT;
    const hf4 k01 = { (_Float16)0.1f, (_Float16)0.1f, (_Float16)0.1f, (_Float16)0.1f };

    float rmax[4][4];
#pragma unroll
    for (int mt = 0; mt < 4; ++mt)
#pragma unroll
        for (int j = 0; j < 4; ++j) rmax[mt][j] = -__builtin_inff();

    float cur[16];
    {
        int gcol = g0 + n;
#pragma unroll
        for (int kf = 0; kf < 4; ++kf)
#pragma unroll
            for (int r = 0; r < 4; ++r)
                cur[kf * 4 + r] = Xrow[(size_t)((kf << 4) + r) * G_TOT + gcol];
    }

#pragma unroll 1
    for (int nt = 0; nt < 8; ++nt) {
        // prefetch next tile while computing this one (uniform branch, no wrap waste)
        float nxt[16];
        if (nt < 7) {
            int gcol = g0 + ((nt + 1) << 4) + n;
#pragma unroll
            for (int kf = 0; kf < 4; ++kf)
#pragma unroll
                for (int r = 0; r < 4; ++r)
                    nxt[kf * 4 + r] = Xrow[(size_t)((kf << 4) + r) * G_TOT + gcol];
        }

        hf4 bf[4];
#pragma unroll
        for (int kf = 0; kf < 4; ++kf) {
            union { hf2 h2[2]; hf4 h4; } u;
            u.h2[0] = pkh(cur[kf * 4 + 0], cur[kf * 4 + 1]);
            u.h2[1] = pkh(cur[kf * 4 + 2], cur[kf * 4 + 3]);
            bf[kf] = u.h4;
        }

#pragma unroll
        for (int l = 0; l < 4; ++l) {
            float4_ acc[4];
#pragma unroll
            for (int mt = 0; mt < 4; ++mt)  // acc init = -bias (quad-broadcast b128)
                acc[mt] = *(const float4_*)&lbias[(l << 6) + (mt << 4) + (q << 2)];
#pragma unroll
            for (int mt = 0; mt < 4; ++mt) {
#pragma unroll
                for (int pr = 0; pr < 2; ++pr) {
                    union { hf8 h8; hf4 h4[2]; } ua;
                    ua.h8 = *(const hf8*)&lws[((((((l << 2) + mt) << 1) + pr) << 6) + lane) << 3];
                    acc[mt] = __builtin_amdgcn_mfma_f32_16x16x16f16(ua.h4[0], bf[(pr << 1) + 0], acc[mt], 0, 0, 0);
                    acc[mt] = __builtin_amdgcn_mfma_f32_16x16x16f16(ua.h4[1], bf[(pr << 1) + 1], acc[mt], 0, 0, 0);
                }
            }
            if (l < 3) {
#pragma unroll
                for (int mt = 0; mt < 4; ++mt) {   // packed-f16 leaky-relu
                    union { hf2 h2[2]; hf4 h4; } u;
                    u.h2[0] = pkh(acc[mt][0], acc[mt][1]);
                    u.h2[1] = pkh(acc[mt][2], acc[mt][3]);
                    hf4 h = u.h4;
                    h = __builtin_elementwise_max(h, h * k01);
                    bf[mt] = h;   // D rows of tile mt == next-layer K-chunk mt
                }
            } else {
                // deferred lrelu: max over G commutes with monotone lrelu,
                // so track raw max and apply lrelu once after reduction
#pragma unroll
                for (int mt = 0; mt < 4; ++mt)
#pragma unroll
                    for (int j = 0; j < 4; ++j)
                        rmax[mt][j] = fmaxf(rmax[mt][j], acc[mt][j]);
            }
        }
        if (nt < 7) {
#pragma unroll
            for (int i = 0; i < 16; ++i) cur[i] = nxt[i];
        }
    }

    // reduce over 16 column-lanes, then apply the deferred lrelu once
#pragma unroll
    for (int mt = 0; mt < 4; ++mt)
#pragma unroll
        for (int j = 0; j < 4; ++j) {
            float v = rmax[mt][j];
            v = fmaxf(v, __shfl_xor(v, 1, 64));
            v = fmaxf(v, __shfl_xor(v, 2, 64));
            v = fmaxf(v, __shfl_xor(v, 4, 64));
            v = fmaxf(v, __shfl_xor(v, 8, 64));
            rmax[mt][j] = fmaxf(v, 0.1f * v);
        }
    if (n == 0) {
#pragma unroll
        for (int mt = 0; mt < 4; ++mt)
#pragma unroll
            for (int j = 0; j < 4; ++j)
                blockmax[w][(mt << 4) + (q << 2) + j] = rmax[mt][j];
    }
    __syncthreads();
    if (tid < 64) {
        float v = fmaxf(fmaxf(blockmax[0][tid], blockmax[1][tid]),
                        fmaxf(blockmax[2][tid], blockmax[3][tid]));
        unsigned s = __float_as_uint(v);
        unsigned enc = (s & 0x80000000u) ? ~s : (s | 0x80000000u);
        atomicMax(&maxenc[b * 64 + tid], enc);
    }
}

__global__ void ge_final(const unsigned* __restrict__ maxenc, float* __restrict__ out)
{
    int i = threadIdx.x;
    if (i < 512) {
        unsigned u = maxenc[i];
        unsigned s = (u & 0x80000000u) ? (u ^ 0x80000000u) : ~u;
        out[i] = __uint_as_float(s);
    }
}

extern "C" void kernel_launch(void* const* d_in, const int* in_sizes, int n_in,
                              void* d_out, int out_size, void* d_ws, size_t ws_size,
                              hipStream_t stream) {
    const float* feat = (const float*)d_in[0];
    const float* W0 = (const float*)d_in[1];
    const float* W1 = (const float*)d_in[2];
    const float* W2 = (const float*)d_in[3];
    const float* W3 = (const float*)d_in[4];
    float* ws = (float*)d_ws;
    unsigned* maxenc = (unsigned*)(ws + 18432);

    ge_prep<<<9, 256, 0, stream>>>(feat, W0, W1, W2, W3, ws);
    ge_main<<<1024, 256, 0, stream>>>(feat, ws, ws + 16384, maxenc);
    ge_final<<<1, 512, 0, stream>>>(maxenc, (float*)d_out);
}